// Round 2
// baseline (460.539 us; speedup 1.0000x reference)
//
#include <hip/hip_runtime.h>
#include <stdint.h>

typedef float f32x4 __attribute__((ext_vector_type(4)));
typedef __bf16 bf16x8 __attribute__((ext_vector_type(8)));
typedef unsigned short ushort_t;
typedef ushort_t ushortx8 __attribute__((ext_vector_type(8)));

#define DEV static __device__ __forceinline__

DEV ushort_t f2bf(float f) {
  union { float f; uint32_t u; } v; v.f = f;
  uint32_t u = v.u;
  return (ushort_t)((u + 0x7FFFu + ((u >> 16) & 1u)) >> 16);
}

DEV void cp16(const void* g, void* l) {
  __builtin_amdgcn_global_load_lds((const __attribute__((address_space(1))) unsigned int*)g,
                                   (__attribute__((address_space(3))) unsigned int*)l,
                                   16, 0, 0);
}

DEV f32x4 mfma16(bf16x8 a, bf16x8 b, f32x4 c) {
  return __builtin_amdgcn_mfma_f32_16x16x32_bf16(a, b, c, 0, 0, 0);
}

// ---------------- convert x (fp32 -> bf16), 8 elems/thread ----------------
__global__ __launch_bounds__(256) void k_cvt_x(const float* __restrict__ x,
                                               ushort_t* __restrict__ xb) {
  size_t idx = ((size_t)blockIdx.x * 256 + threadIdx.x) * 8;
  const float4* src = (const float4*)(x + idx);
  float4 a = src[0], b = src[1];
  ushortx8 o;
  o[0] = f2bf(a.x); o[1] = f2bf(a.y); o[2] = f2bf(a.z); o[3] = f2bf(a.w);
  o[4] = f2bf(b.x); o[5] = f2bf(b.y); o[6] = f2bf(b.z); o[7] = f2bf(b.w);
  *(ushortx8*)(xb + idx) = o;
}

// ---------------- transpose 1024x1024 fp32 -> bf16 [N][K] ----------------
__global__ __launch_bounds__(256) void k_transpose_w(const float* __restrict__ src,
                                                     ushort_t* __restrict__ dst) {
  __shared__ float tile[32][33];
  int tx = threadIdx.x & 31, ty = threadIdx.x >> 5;
  int c0 = blockIdx.x * 32, r0 = blockIdx.y * 32;
#pragma unroll
  for (int i = ty; i < 32; i += 8)
    tile[i][tx] = src[(size_t)(r0 + i) * 1024 + c0 + tx];
  __syncthreads();
#pragma unroll
  for (int i = ty; i < 32; i += 8)
    dst[(size_t)(c0 + i) * 1024 + r0 + tx] = f2bf(tile[tx][i]);
}

// ---------------- GEMM: C[M,N] = A[M,K] * Bt[N,K]^T + bias ----------------
// MODE 0: QKV projection epilogue (scatter to q/k heads layout, v transposed)
// MODE 1: output projection, fp32 result
template <int MODE>
__global__ __launch_bounds__(256, 2) void k_gemm(
    const ushort_t* __restrict__ A, const ushort_t* __restrict__ Bt,
    const float* __restrict__ b0, const float* __restrict__ b1,
    const float* __restrict__ b2, ushort_t* __restrict__ qw,
    ushort_t* __restrict__ kw, ushort_t* __restrict__ vtw,
    float* __restrict__ outf) {
  const int K = 1024;
  __shared__ ushort_t As[128 * 32];
  __shared__ ushort_t Bs[128 * 32];
  int tid = threadIdx.x;
  int w = tid >> 6, lane = tid & 63, l16 = lane & 15, lg = lane >> 4;
  int m0 = blockIdx.x * 128, n0 = blockIdx.y * 128;
  int wm = (w >> 1) * 64, wn = (w & 1) * 64;
  f32x4 acc[4][4] = {};

  const ushort_t* Ag = A + (size_t)(m0 + (tid >> 2)) * K + (tid & 3) * 8;
  const ushort_t* Bg = Bt + (size_t)(n0 + (tid >> 2)) * K + (tid & 3) * 8;

  for (int k0 = 0; k0 < K; k0 += 32) {
    cp16(Ag + k0, As + w * 512);
    cp16(Ag + k0 + 64 * K, As + 2048 + w * 512);
    cp16(Bg + k0, Bs + w * 512);
    cp16(Bg + k0 + 64 * K, Bs + 2048 + w * 512);
    __syncthreads();
    bf16x8 af[4], bfr[4];
#pragma unroll
    for (int i = 0; i < 4; ++i)
      af[i] = *(const bf16x8*)&As[(wm + i * 16 + l16) * 32 + lg * 8];
#pragma unroll
    for (int j = 0; j < 4; ++j)
      bfr[j] = *(const bf16x8*)&Bs[(wn + j * 16 + l16) * 32 + lg * 8];
#pragma unroll
    for (int i = 0; i < 4; ++i)
#pragma unroll
      for (int j = 0; j < 4; ++j)
        acc[i][j] = mfma16(af[i], bfr[j], acc[i][j]);
    __syncthreads();
  }

  if (MODE == 0) {
    int p = n0 >> 10;  // 0=q 1=k 2=v (uniform per block: 1024 % 128 == 0)
    const float* bias = (p == 0) ? b0 : (p == 1) ? b1 : b2;
    int c0 = n0 & 1023;
#pragma unroll
    for (int j = 0; j < 4; ++j) {
      int col = c0 + wn + j * 16 + l16;  // 0..1023 within projection
      float bb = bias[col];
      int h = col >> 6, dh = col & 63;
#pragma unroll
      for (int i = 0; i < 4; ++i) {
#pragma unroll
        for (int r = 0; r < 4; ++r) {
          int row = m0 + wm + i * 16 + lg * 4 + r;  // token index
          int bi = row >> 11, s = row & 2047;
          float val = acc[i][j][r] + bb;
          if (p == 0)
            qw[((size_t)(bi * 16 + h) * 2048 + s) * 64 + dh] = f2bf(val);
          else if (p == 1)
            kw[((size_t)(bi * 16 + h) * 2048 + s) * 64 + dh] = f2bf(val);
          else
            vtw[((size_t)(bi * 16 + h) * 64 + dh) * 2048 + s] = f2bf(val);
        }
      }
    }
  } else {
#pragma unroll
    for (int j = 0; j < 4; ++j) {
      int col = n0 + wn + j * 16 + l16;
      float bb = b0[col];
#pragma unroll
      for (int i = 0; i < 4; ++i) {
#pragma unroll
        for (int r = 0; r < 4; ++r) {
          int row = m0 + wm + i * 16 + lg * 4 + r;
          outf[(size_t)row * 1024 + col] = acc[i][j][r] + bb;
        }
      }
    }
  }
}

// ---------------- flash attention forward ----------------
// grid: (S/128, B*H). block 256 = 4 waves; wave owns 32 q-rows (2 strips of 16).
// q,k: [bh][s][64] bf16 ; vt: [bh][64][s] bf16 ; att out: [token][1024] bf16
__global__ __launch_bounds__(256, 2) void k_attn(
    const ushort_t* __restrict__ qg, const ushort_t* __restrict__ kg,
    const ushort_t* __restrict__ vtg, ushort_t* __restrict__ att) {
  __shared__ ushort_t Ks[128 * 72];     // [key][dh], stride 72 (pad 8)
  __shared__ ushort_t Vs[64 * 136];     // [dh][key], stride 136 (pad 8)
  __shared__ ushort_t Ps[4][16 * 136];  // per-wave P strip buffer
  int tid = threadIdx.x;
  int w = tid >> 6, lane = tid & 63, l16 = lane & 15, lg = lane >> 4;
  int bh = blockIdx.y;
  int q0 = blockIdx.x * 128;
  const ushort_t* qh = qg + (size_t)bh * 2048 * 64;
  const ushort_t* kh = kg + (size_t)bh * 2048 * 64;
  const ushort_t* vh = vtg + (size_t)bh * 64 * 2048;

  // Q fragments, loaded once (A-operand layout: m=l16, k=lg*8..+7 per kstep)
  bf16x8 qf[2][2];
#pragma unroll
  for (int st = 0; st < 2; ++st)
#pragma unroll
    for (int ks = 0; ks < 2; ++ks)
      qf[st][ks] = *(const bf16x8*)(qh + (size_t)(q0 + w * 32 + st * 16 + l16) * 64 +
                                    ks * 32 + lg * 8);

  f32x4 o[2][4] = {};
  f32x4 m_[2], l_[2];
#pragma unroll
  for (int st = 0; st < 2; ++st)
#pragma unroll
    for (int r = 0; r < 4; ++r) { m_[st][r] = -3.0e38f; l_[st][r] = 0.f; }

  const float SCALE = 0.125f;       // 1/sqrt(64)
  const float L2E = 1.44269504f;    // log2(e)

  for (int kb = 0; kb < 2048; kb += 128) {
    __syncthreads();
    // stage K tile: 128 keys x 64 dh
#pragma unroll
    for (int i = 0; i < 4; ++i) {
      int row = (tid >> 3) + i * 32;
      int ch = (tid & 7) * 8;
      *(bf16x8*)&Ks[row * 72 + ch] =
          *(const bf16x8*)(kh + (size_t)(kb + row) * 64 + ch);
    }
    // stage Vt tile: 64 dh x 128 keys
#pragma unroll
    for (int i = 0; i < 4; ++i) {
      int row = (tid >> 4) + i * 16;
      int ch = (tid & 15) * 8;
      *(bf16x8*)&Vs[row * 136 + ch] =
          *(const bf16x8*)(vh + (size_t)row * 2048 + kb + ch);
    }
    __syncthreads();

    // scores: S[q][key] for 2 strips x 8 col-tiles
    f32x4 sc[2][8] = {};
#pragma unroll
    for (int j = 0; j < 8; ++j) {
      bf16x8 kf0 = *(const bf16x8*)&Ks[(j * 16 + l16) * 72 + lg * 8];
      bf16x8 kf1 = *(const bf16x8*)&Ks[(j * 16 + l16) * 72 + 32 + lg * 8];
      sc[0][j] = mfma16(qf[0][0], kf0, sc[0][j]);
      sc[0][j] = mfma16(qf[0][1], kf1, sc[0][j]);
      sc[1][j] = mfma16(qf[1][0], kf0, sc[1][j]);
      sc[1][j] = mfma16(qf[1][1], kf1, sc[1][j]);
    }

#pragma unroll
    for (int st = 0; st < 2; ++st) {
#pragma unroll
      for (int j = 0; j < 8; ++j) sc[st][j] *= SCALE;
      // row max (row lives in a 16-lane group; per-reg)
      f32x4 mx = sc[st][0];
#pragma unroll
      for (int j = 1; j < 8; ++j)
#pragma unroll
        for (int r = 0; r < 4; ++r) mx[r] = fmaxf(mx[r], sc[st][j][r]);
      for (int d = 1; d < 16; d <<= 1)
#pragma unroll
        for (int r = 0; r < 4; ++r) mx[r] = fmaxf(mx[r], __shfl_xor(mx[r], d));
      f32x4 mn, al;
#pragma unroll
      for (int r = 0; r < 4; ++r) {
        mn[r] = fmaxf(m_[st][r], mx[r]);
        al[r] = exp2f((m_[st][r] - mn[r]) * L2E);
        m_[st][r] = mn[r];
      }
      f32x4 rs = {0.f, 0.f, 0.f, 0.f};
#pragma unroll
      for (int j = 0; j < 8; ++j)
#pragma unroll
        for (int r = 0; r < 4; ++r) {
          float pv = exp2f((sc[st][j][r] - mn[r]) * L2E);
          sc[st][j][r] = pv;
          rs[r] += pv;
        }
      for (int d = 1; d < 16; d <<= 1)
#pragma unroll
        for (int r = 0; r < 4; ++r) rs[r] += __shfl_xor(rs[r], d);
#pragma unroll
      for (int r = 0; r < 4; ++r) l_[st][r] = l_[st][r] * al[r] + rs[r];
#pragma unroll
      for (int dt = 0; dt < 4; ++dt)
#pragma unroll
        for (int r = 0; r < 4; ++r) o[st][dt][r] *= al[r];
      // write P strip (C-layout -> LDS row-major [qrow][key])
#pragma unroll
      for (int j = 0; j < 8; ++j)
#pragma unroll
        for (int r = 0; r < 4; ++r)
          Ps[w][(lg * 4 + r) * 136 + j * 16 + l16] = f2bf(sc[st][j][r]);
      // PV: O[q][dh] += P[q][key] * V[key][dh]
#pragma unroll
      for (int ks = 0; ks < 4; ++ks) {
        bf16x8 pf = *(const bf16x8*)&Ps[w][l16 * 136 + ks * 32 + lg * 8];
#pragma unroll
        for (int dt = 0; dt < 4; ++dt) {
          bf16x8 vf = *(const bf16x8*)&Vs[(dt * 16 + l16) * 136 + ks * 32 + lg * 8];
          o[st][dt] = mfma16(pf, vf, o[st][dt]);
        }
      }
    }
  }

  // epilogue: O /= l, scatter to [token][1024] bf16
  int bi = bh >> 4, h = bh & 15;
#pragma unroll
  for (int st = 0; st < 2; ++st) {
    f32x4 inv;
#pragma unroll
    for (int r = 0; r < 4; ++r) inv[r] = 1.0f / l_[st][r];
#pragma unroll
    for (int dt = 0; dt < 4; ++dt)
#pragma unroll
      for (int r = 0; r < 4; ++r) {
        int srow = q0 + w * 32 + st * 16 + lg * 4 + r;
        int col = h * 64 + dt * 16 + l16;
        att[(size_t)(bi * 2048 + srow) * 1024 + col] = f2bf(o[st][dt][r] * inv[r]);
      }
  }
}

// ---------------- host ----------------
extern "C" void kernel_launch(void* const* d_in, const int* in_sizes, int n_in,
                              void* d_out, int out_size, void* d_ws, size_t ws_size,
                              hipStream_t stream) {
  const float* x = (const float*)d_in[0];
  const float* wq = (const float*)d_in[1];
  const float* bq = (const float*)d_in[2];
  const float* wk = (const float*)d_in[3];
  const float* bk = (const float*)d_in[4];
  const float* wv = (const float*)d_in[5];
  const float* bv = (const float*)d_in[6];
  const float* wo = (const float*)d_in[7];
  const float* bo = (const float*)d_in[8];
  float* out = (float*)d_out;

  char* ws = (char*)d_ws;
  ushort_t* xb = (ushort_t*)(ws);                       // 16 MiB
  ushort_t* wqkvT = (ushort_t*)(ws + 16777216);         // 6 MiB ([3072][1024])
  ushort_t* woT = (ushort_t*)(ws + 23068672);           // 2 MiB ([1024][1024])
  ushort_t* qw = (ushort_t*)(ws + 25165824);            // 16 MiB
  ushort_t* kw = (ushort_t*)(ws + 41943040);            // 16 MiB
  ushort_t* vtw = (ushort_t*)(ws + 58720256);           // 16 MiB
  ushort_t* att = (ushort_t*)(ws + 75497472);           // 16 MiB

  k_cvt_x<<<dim3(4096), dim3(256), 0, stream>>>(x, xb);
  k_transpose_w<<<dim3(32, 32), dim3(256), 0, stream>>>(wq, wqkvT);
  k_transpose_w<<<dim3(32, 32), dim3(256), 0, stream>>>(wk, wqkvT + 1024 * 1024);
  k_transpose_w<<<dim3(32, 32), dim3(256), 0, stream>>>(wv, wqkvT + 2 * 1024 * 1024);
  k_transpose_w<<<dim3(32, 32), dim3(256), 0, stream>>>(wo, woT);

  k_gemm<0><<<dim3(64, 24), dim3(256), 0, stream>>>(
      xb, wqkvT, bq, bk, bv, qw, kw, vtw, nullptr);

  k_attn<<<dim3(16, 64), dim3(256), 0, stream>>>(qw, kw, vtw, att);

  k_gemm<1><<<dim3(64, 8), dim3(256), 0, stream>>>(
      att, woT, bo, nullptr, nullptr, nullptr, nullptr, nullptr, out);
}